// Round 4
// baseline (94.868 us; speedup 1.0000x reference)
//
#include <hip/hip_runtime.h>

// Bessel order-5 IIR -> truncated FIR.
// Digital pole max magnitude ~0.640 -> tail after K taps ~0.64^K.
// K=24: truncation error ~1e-4 absolute (threshold 7.5e-2, observed margin 5x).
// Linearity: xmax * lfilter(x/xmax) == lfilter(x) -> skip normalization.

#define K_TAPS 24
#define OPT 16                    // outputs per thread
#define BLOCK 256
#define OPB (BLOCK * OPT)         // 4096 outputs per block
#define T_LEN 1048576
#define BATCH 16
#define TILES_PER_ROW (T_LEN / OPB)   // 256
#define NV ((OPT + K_TAPS) / 4)       // 10 float4 window loads

typedef float fx4 __attribute__((ext_vector_type(4)));  // native vec for builtins

__global__ void bessel_make_h(const float* __restrict__ b,
                              const float* __restrict__ a,
                              float* __restrict__ h) {
    if (threadIdx.x != 0 || blockIdx.x != 0) return;
    float bb[6], aa[6];
    float inv = 1.0f / a[0];
#pragma unroll
    for (int i = 0; i < 6; ++i) { bb[i] = b[i] * inv; aa[i] = a[i] * inv; }
    float z0 = 0.f, z1 = 0.f, z2 = 0.f, z3 = 0.f, z4 = 0.f;
    for (int t = 0; t < K_TAPS; ++t) {
        float xt = (t == 0) ? 1.0f : 0.0f;
        float yv = fmaf(bb[0], xt, z0);
        z0 = fmaf(bb[1], xt, z1) - aa[1] * yv;
        z1 = fmaf(bb[2], xt, z2) - aa[2] * yv;
        z2 = fmaf(bb[3], xt, z3) - aa[3] * yv;
        z3 = fmaf(bb[4], xt, z4) - aa[4] * yv;
        z4 = bb[5] * xt - aa[5] * yv;
        h[t] = yv;
    }
}

__global__ __launch_bounds__(BLOCK, 2) void bessel_fir(
    const float* __restrict__ x, const float* __restrict__ h,
    float* __restrict__ y) {
    const int bid  = blockIdx.x;
    const int row  = bid >> 8;                    // TILES_PER_ROW = 256
    const int tile = bid & (TILES_PER_ROW - 1);
    const int G    = tile * OPB + (int)threadIdx.x * OPT;
    const float* __restrict__ xr = x + (size_t)row * T_LEN;
    float* __restrict__ yr       = y + (size_t)row * T_LEN;

    // window w[i] = x[G - K + i], i in [0, OPT+K)
    float w[OPT + K_TAPS];
    float hs[K_TAPS];
    if (G >= K_TAPS) {
        // (G-24)*4 bytes is 16B-aligned since G % 16 == 0
        const fx4* p = (const fx4*)(xr + (G - K_TAPS));
        fx4 v[NV];
#pragma unroll
        for (int i = 0; i < NV; ++i) v[i] = p[i];
        // fence: no instruction may be scheduled across this point ->
        // all NV loads issue back-to-back, one latency exposure per wave
        __builtin_amdgcn_sched_barrier(0);
#pragma unroll
        for (int k = 0; k < K_TAPS; ++k) hs[k] = h[k];   // wave-uniform -> SGPR
#pragma unroll
        for (int i = 0; i < NV; ++i) {
            w[4 * i + 0] = v[i].x;
            w[4 * i + 1] = v[i].y;
            w[4 * i + 2] = v[i].z;
            w[4 * i + 3] = v[i].w;
        }
    } else {
        // row start (2 threads per row): zero initial state == zero padding
#pragma unroll
        for (int k = 0; k < K_TAPS; ++k) hs[k] = h[k];
#pragma unroll
        for (int i = 0; i < OPT + K_TAPS; ++i) {
            int gi = G - K_TAPS + i;
            w[i] = (gi >= 0) ? xr[gi] : 0.0f;
        }
    }

    float acc[OPT];
#pragma unroll
    for (int j = 0; j < OPT; ++j) acc[j] = 0.0f;

    // k-outer, j-inner: 16 independent FMA chains per tap
#pragma unroll
    for (int k = 0; k < K_TAPS; ++k) {
#pragma unroll
        for (int j = 0; j < OPT; ++j)
            acc[j] = fmaf(hs[k], w[K_TAPS + j - k], acc[j]);
    }

    // streaming output, never re-read: nontemporal -> keep L2/L3 for x
    fx4* oy = (fx4*)(yr + G);
#pragma unroll
    for (int q = 0; q < OPT / 4; ++q) {
        fx4 o = {acc[4 * q + 0], acc[4 * q + 1], acc[4 * q + 2], acc[4 * q + 3]};
        __builtin_nontemporal_store(o, &oy[q]);
    }
}

extern "C" void kernel_launch(void* const* d_in, const int* in_sizes, int n_in,
                              void* d_out, int out_size, void* d_ws, size_t ws_size,
                              hipStream_t stream) {
    const float* x = (const float*)d_in[0];
    const float* b = (const float*)d_in[1];
    const float* a = (const float*)d_in[2];
    float* y = (float*)d_out;
    float* h = (float*)d_ws;   // K_TAPS floats of scratch

    hipLaunchKernelGGL(bessel_make_h, dim3(1), dim3(64), 0, stream, b, a, h);
    hipLaunchKernelGGL(bessel_fir, dim3(BATCH * TILES_PER_ROW), dim3(BLOCK), 0,
                       stream, x, h, y);
}

// Round 5
// 64.178 us; speedup vs baseline: 1.4782x; 1.4782x over previous
//
#include <hip/hip_runtime.h>

// Bessel order-5 IIR -> truncated FIR (K=24 taps; pole max |p|~0.64 -> tail ~1e-4,
// threshold 7.5e-2). Linearity: xmax*lfilter(x/xmax)==lfilter(x) -> skip norm.
//
// Work assignment: ONE float4 of outputs per thread (lane-stride layout) so every
// wave-level global load/store is a single contiguous 1KB transaction. R4 showed
// the blocked layout (16 consecutive outputs/thread) makes all accesses 64B-strided.

#define K_TAPS 24
#define BLOCK 256
#define T_LEN 1048576
#define BATCH 16
#define F4_PER_ROW (T_LEN / 4)          // 262144 = 2^18
#define NV 7                            // float4 loads per thread (28-float window)

typedef float fx4 __attribute__((ext_vector_type(4)));

__global__ void bessel_make_h(const float* __restrict__ b,
                              const float* __restrict__ a,
                              float* __restrict__ h) {
    if (threadIdx.x != 0 || blockIdx.x != 0) return;
    float bb[6], aa[6];
    float inv = 1.0f / a[0];
#pragma unroll
    for (int i = 0; i < 6; ++i) { bb[i] = b[i] * inv; aa[i] = a[i] * inv; }
    float z0 = 0.f, z1 = 0.f, z2 = 0.f, z3 = 0.f, z4 = 0.f;
    for (int t = 0; t < K_TAPS; ++t) {
        float xt = (t == 0) ? 1.0f : 0.0f;
        float yv = fmaf(bb[0], xt, z0);
        z0 = fmaf(bb[1], xt, z1) - aa[1] * yv;
        z1 = fmaf(bb[2], xt, z2) - aa[2] * yv;
        z2 = fmaf(bb[3], xt, z3) - aa[3] * yv;
        z3 = fmaf(bb[4], xt, z4) - aa[4] * yv;
        z4 = bb[5] * xt - aa[5] * yv;
        h[t] = yv;
    }
}

__global__ __launch_bounds__(BLOCK, 8) void bessel_fir(
    const float* __restrict__ x, const float* __restrict__ h,
    float* __restrict__ y) {
    const int gid = blockIdx.x * BLOCK + (int)threadIdx.x;  // global float4 index
    const int row = gid >> 18;                               // F4_PER_ROW = 2^18
    const int p   = (gid & (F4_PER_ROW - 1)) * 4;            // first output idx in row
    const float* __restrict__ xr = x + (size_t)row * T_LEN;
    float* __restrict__ yr       = y + (size_t)row * T_LEN;

    // w[i] = x[p - 24 + i], i in [0, 28): covers x[p-23 .. p+3] (w[0] is slack)
    float w[4 + K_TAPS];
    float hs[K_TAPS];
    if (p >= K_TAPS) {
        const fx4* src = (const fx4*)(xr + (p - K_TAPS));    // 16B-aligned (p%4==0)
        fx4 v[NV];
#pragma unroll
        for (int i = 0; i < NV; ++i) v[i] = src[i];          // 7 coalesced 1KB/wave loads
        __builtin_amdgcn_sched_barrier(0);                   // keep the burst together
#pragma unroll
        for (int k = 0; k < K_TAPS; ++k) hs[k] = h[k];       // wave-uniform -> SGPR
#pragma unroll
        for (int i = 0; i < NV; ++i) {
            w[4 * i + 0] = v[i].x;
            w[4 * i + 1] = v[i].y;
            w[4 * i + 2] = v[i].z;
            w[4 * i + 3] = v[i].w;
        }
    } else {
        // row start (6 threads per row): zero initial state == zero padding
#pragma unroll
        for (int k = 0; k < K_TAPS; ++k) hs[k] = h[k];
#pragma unroll
        for (int i = 0; i < 4 + K_TAPS; ++i) {
            int gi = p - K_TAPS + i;
            w[i] = (gi >= 0) ? xr[gi] : 0.0f;
        }
    }

    float acc[4] = {0.f, 0.f, 0.f, 0.f};
#pragma unroll
    for (int k = 0; k < K_TAPS; ++k) {
#pragma unroll
        for (int j = 0; j < 4; ++j)
            acc[j] = fmaf(hs[k], w[K_TAPS + j - k], acc[j]);
    }

    fx4 o = {acc[0], acc[1], acc[2], acc[3]};
    *(fx4*)(yr + p) = o;                                     // coalesced 1KB/wave store
}

extern "C" void kernel_launch(void* const* d_in, const int* in_sizes, int n_in,
                              void* d_out, int out_size, void* d_ws, size_t ws_size,
                              hipStream_t stream) {
    const float* x = (const float*)d_in[0];
    const float* b = (const float*)d_in[1];
    const float* a = (const float*)d_in[2];
    float* y = (float*)d_out;
    float* h = (float*)d_ws;   // K_TAPS floats of scratch

    const int grid = (BATCH * F4_PER_ROW) / BLOCK;           // 16384 blocks
    hipLaunchKernelGGL(bessel_make_h, dim3(1), dim3(64), 0, stream, b, a, h);
    hipLaunchKernelGGL(bessel_fir, dim3(grid), dim3(BLOCK), 0, stream, x, h, y);
}

// Round 6
// 33.081 us; speedup vs baseline: 2.8678x; 1.9400x over previous
//
#include <hip/hip_runtime.h>

// Bessel order-5 IIR -> truncated FIR (K=24; max pole |p|~0.64 -> tail ~1e-4
// vs threshold 7.5e-2). Linearity: xmax*lfilter(x/xmax)==lfilter(x) -> no norm.
//
// Single fused kernel. Blocked layout (16 consecutive outputs/thread) — R5
// proved the lane-stride layout triples TCC write traffic; R2's blocked form
// measured WRITE=65MB. Load burst first, then the per-wave redundant impulse-
// response IIR (serial ~500cy) runs while loads are in flight: latency filler.

#define K_TAPS 24
#define OPT 16                        // outputs per thread
#define BLOCK 256
#define OPB (BLOCK * OPT)             // 4096 outputs per block
#define T_LEN 1048576
#define BATCH 16
#define TILES_PER_ROW (T_LEN / OPB)   // 256
#define NW (OPT + K_TAPS)             // 40-float window
#define NV (NW / 4)                   // 10 float4 loads

typedef float fx4 __attribute__((ext_vector_type(4)));

__global__ __launch_bounds__(BLOCK, 4) void bessel_fused(
    const float* __restrict__ x, const float* __restrict__ bcoef,
    const float* __restrict__ acoef, float* __restrict__ y) {
    const int bid  = blockIdx.x;
    const int row  = bid >> 8;                    // TILES_PER_ROW = 256
    const int tile = bid & (TILES_PER_ROW - 1);
    const int G    = tile * OPB + (int)threadIdx.x * OPT;
    const float* __restrict__ xr = x + (size_t)row * T_LEN;
    float* __restrict__ yr       = y + (size_t)row * T_LEN;

    // ---- phase 1: issue the whole window load burst ----
    // w[i] = x[G-24+i]; (G-24)*4B is 16B-aligned (G % 16 == 0)
    fx4 v[NV];
    if (G >= K_TAPS) {
        const fx4* src = (const fx4*)(xr + (G - K_TAPS));
#pragma unroll
        for (int i = 0; i < NV; ++i) v[i] = src[i];
    } else {
        // row start (2 threads per row): zero initial state == zero padding
        float tmp[NW];
#pragma unroll
        for (int i = 0; i < NW; ++i) {
            int gi = G - K_TAPS + i;
            tmp[i] = (gi >= 0) ? xr[gi] : 0.0f;
        }
#pragma unroll
        for (int i = 0; i < NV; ++i)
            v[i] = (fx4){tmp[4*i], tmp[4*i+1], tmp[4*i+2], tmp[4*i+3]};
    }
    __builtin_amdgcn_sched_barrier(0);   // loads stay clustered above this line

    // ---- phase 2: impulse response h[0..K) in-register (uniform, redundant
    // per wave) — serial VALU chain hides the load latency ----
    float bb[6], aa[6];
    float inv = 1.0f / acoef[0];
#pragma unroll
    for (int i = 0; i < 6; ++i) { bb[i] = bcoef[i] * inv; aa[i] = acoef[i] * inv; }
    float hs[K_TAPS];
    {
        float z0 = 0.f, z1 = 0.f, z2 = 0.f, z3 = 0.f, z4 = 0.f;
#pragma unroll
        for (int t = 0; t < K_TAPS; ++t) {
            float xt = (t == 0) ? 1.0f : 0.0f;
            float yv = fmaf(bb[0], xt, z0);
            z0 = fmaf(bb[1], xt, z1) - aa[1] * yv;
            z1 = fmaf(bb[2], xt, z2) - aa[2] * yv;
            z2 = fmaf(bb[3], xt, z3) - aa[3] * yv;
            z3 = fmaf(bb[4], xt, z4) - aa[4] * yv;
            z4 = bb[5] * xt - aa[5] * yv;
            hs[t] = yv;
        }
    }

    // ---- phase 3: unpack window, 16 independent FMA chains per tap ----
    float w[NW];
#pragma unroll
    for (int i = 0; i < NV; ++i) {
        w[4*i + 0] = v[i].x;
        w[4*i + 1] = v[i].y;
        w[4*i + 2] = v[i].z;
        w[4*i + 3] = v[i].w;
    }
    float acc[OPT];
#pragma unroll
    for (int j = 0; j < OPT; ++j) acc[j] = 0.0f;
#pragma unroll
    for (int k = 0; k < K_TAPS; ++k) {
#pragma unroll
        for (int j = 0; j < OPT; ++j)
            acc[j] = fmaf(hs[k], w[K_TAPS + j - k], acc[j]);
    }

    // ---- phase 4: plain cached stores (R2-proven: WRITE=65MB; nt tripled it) ----
    fx4* oy = (fx4*)(yr + G);
#pragma unroll
    for (int q = 0; q < OPT / 4; ++q) {
        fx4 o = {acc[4*q], acc[4*q+1], acc[4*q+2], acc[4*q+3]};
        oy[q] = o;
    }
}

extern "C" void kernel_launch(void* const* d_in, const int* in_sizes, int n_in,
                              void* d_out, int out_size, void* d_ws, size_t ws_size,
                              hipStream_t stream) {
    const float* x = (const float*)d_in[0];
    const float* b = (const float*)d_in[1];
    const float* a = (const float*)d_in[2];
    float* y = (float*)d_out;

    hipLaunchKernelGGL(bessel_fused, dim3(BATCH * TILES_PER_ROW), dim3(BLOCK), 0,
                       stream, x, b, a, y);
}